// Round 3
// baseline (800.487 us; speedup 1.0000x reference)
//
#include <hip/hip_runtime.h>
#include <hip/hip_bf16.h>
#include <hip/hip_fp16.h>

// Problem constants (TempoAttention: N=8, T=1024, D=128, H=8)
#define NB 8
#define TT 1024
#define DD 128
#define HH 8

using short8  = __attribute__((ext_vector_type(8))) short;    // 8 bf16 (4 VGPRs)
using floatx4 = __attribute__((ext_vector_type(4))) float;    // MFMA C/D
using half8   = __attribute__((ext_vector_type(8))) _Float16;

// fp32 -> bf16 (RNE)
__device__ __forceinline__ unsigned short f2bf_u(float f) {
    union { float f; unsigned u; } v; v.f = f;
    return (unsigned short)((v.u + 0x7fffu + ((v.u >> 16) & 1u)) >> 16);
}

// ---------------------------------------------------------------------------
// One-shot W -> bf16 conversion (proj re-converted W 128x redundantly before).
// Wb layout: [3][1024][128] bf16. 98304 threads, one float4 each.
// ---------------------------------------------------------------------------
__global__ __launch_bounds__(256) void convw_kernel(
    const float* __restrict__ Wq, const float* __restrict__ Wk,
    const float* __restrict__ Wv, unsigned short* __restrict__ Wb)
{
    int idx = blockIdx.x * 256 + threadIdx.x;     // one float4
    const int NW = HH * DD * DD / 4;              // 32768
    const float* src; unsigned short* dst; int off = idx;
    if (idx < NW)          { src = Wq; dst = Wb; }
    else if (idx < 2 * NW) { src = Wk; dst = Wb + HH * DD * DD;     off = idx - NW; }
    else                   { src = Wv; dst = Wb + 2 * HH * DD * DD; off = idx - 2 * NW; }
    float4 v = ((const float4*)src)[off];
    union { unsigned short u[4]; uint2 w; } o;
    o.u[0] = f2bf_u(v.x); o.u[1] = f2bf_u(v.y);
    o.u[2] = f2bf_u(v.z); o.u[3] = f2bf_u(v.w);
    *(uint2*)(dst + (size_t)off * 4) = o.w;
}

// ---------------------------------------------------------------------------
// Projection kernel: q = x@Wq^T+bq etc. -> bf16 in MFMA-friendly layouts.
//   q,k : [n,h,t,d]  (row = token, contiguous d)
//   v   : [n,h,d,t]  (transposed so PV B-fragments are contiguous along t)
// B-fragments now loaded directly as bf16 short8 (no per-block conversion).
// Fragment/epilogue mappings VERIFIED in R1/R2 — unchanged.
// ---------------------------------------------------------------------------
__global__ __launch_bounds__(256, 4) void proj_kernel(
    const float* __restrict__ x, const unsigned short* __restrict__ Wb,
    const float* __restrict__ bq, const float* __restrict__ bk,
    const float* __restrict__ bv,
    unsigned short* __restrict__ qb, unsigned short* __restrict__ kb,
    unsigned short* __restrict__ vt)
{
    int b     = blockIdx.x;
    int which = b >> 10;          // 0=q 1=k 2=v
    int rem   = b & 1023;
    int mblk  = rem >> 3;         // 0..127 (64 rows each)
    int nblk  = rem & 7;          // 0..7   (128 cols each)
    int tid   = threadIdx.x;
    int wid   = tid >> 6, lane = tid & 63;
    int l15   = lane & 15, quad = lane >> 4;
    int m0    = mblk * 64 + wid * 16;

    const unsigned short* W = Wb + (size_t)which * HH * DD * DD;
    const float* bias = (which == 0) ? bq : (which == 1) ? bk : bv;
    unsigned short* dst = (which == 0) ? qb : (which == 1) ? kb : vt;

    // A fragments: x rows (fp32 -> bf16), A[m=l15][k=quad*8+j]
    short8 a[4];
    const float* xr = x + (size_t)(m0 + l15) * DD + quad * 8;
    #pragma unroll
    for (int kk = 0; kk < 4; ++kk) {
        const float* p = xr + kk * 32;
        short8 t;
        #pragma unroll
        for (int j = 0; j < 8; ++j) t[j] = (short)f2bf_u(p[j]);
        a[kk] = t;
    }

    floatx4 acc[8];
    #pragma unroll
    for (int ct = 0; ct < 8; ++ct) acc[ct] = (floatx4){0.f, 0.f, 0.f, 0.f};

    for (int ct = 0; ct < 8; ++ct) {
        int c = nblk * 128 + ct * 16 + l15;          // output channel (B n-index)
        const unsigned short* wr = W + (size_t)c * DD + quad * 8;
        #pragma unroll
        for (int kk = 0; kk < 4; ++kk) {
            short8 bf = *(const short8*)(wr + kk * 32);
            acc[ct] = __builtin_amdgcn_mfma_f32_16x16x32_bf16(a[kk], bf, acc[ct], 0, 0, 0);
        }
    }

    // Epilogue: C/D layout col=l15, row=quad*4+r
    #pragma unroll
    for (int ct = 0; ct < 8; ++ct) {
        int c  = nblk * 128 + ct * 16 + l15;
        int h  = c >> 7, dd = c & 127;
        float bsv = bias[c];
        #pragma unroll
        for (int r = 0; r < 4; ++r) {
            int m = m0 + quad * 4 + r;
            int n = m >> 10, t = m & 1023;
            unsigned short v = f2bf_u(acc[ct][r] + bsv);
            size_t idx;
            if (which == 2) idx = ((size_t)(n * HH + h) * DD + dd) * TT + t;   // v^T
            else            idx = ((size_t)(n * HH + h) * TT + t) * DD + dd;   // q,k
            dst[idx] = v;
        }
    }
}

// ---------------------------------------------------------------------------
// Fused attention kernel. One block = (n,h) x 16 query rows (was 32 -> LDS
// 66->33 KB -> 4 blocks/CU -> 50% occupancy ceiling). 256 threads.
// LDS: S[16][1032] fp16 scores (overwritten with bf16 e-bits) + rowinv[16].
// ---------------------------------------------------------------------------
#define SSTRIDE 1032  // halves; +8 pad breaks power-of-2 bank aliasing

__global__ __launch_bounds__(256, 4) void attn_kernel(
    const unsigned short* __restrict__ qb, const unsigned short* __restrict__ kb,
    const unsigned short* __restrict__ vt,
    const float* __restrict__ wts, const int* __restrict__ mask,
    float* __restrict__ out, float* __restrict__ outagg, float* __restrict__ att)
{
    extern __shared__ char smem[];
    _Float16* S   = (_Float16*)smem;
    float* rowinv = (float*)(smem + 16 * SSTRIDE * 2);

    // XCD swizzle: all 64 tiles of one (n,h) group land on one XCD (b%8)
    int b    = blockIdx.x;
    int slot = b & 7, j = b >> 3;
    int tile = j & 63, gq = j >> 6;
    int g    = gq * 8 + slot;          // n*H + h, 0..63
    int n    = g >> 3, h = g & 7;
    int t0   = tile * 16;

    int tid = threadIdx.x;
    int wid = tid >> 6, lane = tid & 63;
    int l15 = lane & 15, quad = lane >> 4;

    const unsigned short* qp = qb + ((size_t)g * TT + t0) * DD;
    const unsigned short* kp = kb + (size_t)g * TT * DD;
    const unsigned short* vp = vt + (size_t)g * DD * TT;
    const float* wp = wts + (size_t)g * TT * TT + (size_t)t0 * TT;
    const int*   mp = mask + n * TT;
    float* attp = att + (size_t)g * TT * TT + (size_t)t0 * TT;

    // ---- Phase 1: S = mask(weights * scale * (Q K^T)) ----
    short8 aq[4];
    #pragma unroll
    for (int kk = 0; kk < 4; ++kk)
        aq[kk] = *(const short8*)(qp + (size_t)l15 * DD + kk * 32 + quad * 8);

    const int c0 = wid * 256;                 // each wave owns a 256-key strip
    const float scale = 0.08838834764831845f; // 1/sqrt(128)
    for (int ct = 0; ct < 16; ++ct) {
        int scol = c0 + ct * 16;
        int mk = mp[scol + l15];              // nonzero => masked (-inf)
        float w0[4];                          // issue HBM stream loads early
        #pragma unroll
        for (int r = 0; r < 4; ++r)
            w0[r] = wp[(size_t)(quad * 4 + r) * TT + scol + l15];
        floatx4 acc = {0.f, 0.f, 0.f, 0.f};
        #pragma unroll
        for (int kk = 0; kk < 4; ++kk) {
            short8 bf = *(const short8*)(kp + (size_t)(scol + l15) * DD + kk * 32 + quad * 8);
            acc = __builtin_amdgcn_mfma_f32_16x16x32_bf16(aq[kk], bf, acc, 0, 0, 0);
        }
        #pragma unroll
        for (int r = 0; r < 4; ++r) {
            int row = quad * 4 + r;
            float s = mk ? -65504.f : acc[r] * scale * w0[r];
            S[row * SSTRIDE + scol + l15] = (_Float16)s;
        }
    }
    __syncthreads();

    // ---- Phase 2: softmax. 16 lanes per row -> shfl xor 1/2/4/8 (in-wave).
    // Pass A: row max. Pass B: exp-sum. Pass C: write att fp32 straight from
    // registers and store bf16-e bits into S for PV. (Verified R2.)
    int row = tid >> 4;          // 0..15
    int jj  = tid & 15;          // 0..15, owns cols {jj*8 + i*128 + e}
    _Float16* Srow = S + row * SSTRIDE + jj * 8;

    float mx = -3.0e38f;
    #pragma unroll
    for (int i = 0; i < 8; ++i) {
        half8 hv = *(const half8*)(Srow + i * 128);
        #pragma unroll
        for (int e = 0; e < 8; ++e) mx = fmaxf(mx, (float)hv[e]);
    }
    mx = fmaxf(mx, __shfl_xor(mx, 1));
    mx = fmaxf(mx, __shfl_xor(mx, 2));
    mx = fmaxf(mx, __shfl_xor(mx, 4));
    mx = fmaxf(mx, __shfl_xor(mx, 8));

    float sum = 0.f;
    #pragma unroll
    for (int i = 0; i < 8; ++i) {
        half8 hv = *(const half8*)(Srow + i * 128);
        #pragma unroll
        for (int e = 0; e < 8; ++e) sum += __expf((float)hv[e] - mx);
    }
    sum += __shfl_xor(sum, 1);
    sum += __shfl_xor(sum, 2);
    sum += __shfl_xor(sum, 4);
    sum += __shfl_xor(sum, 8);
    float iv = 1.f / sum;
    if (jj == 0) rowinv[row] = iv;

    float* arow = attp + (size_t)row * TT + jj * 8;
    #pragma unroll 2
    for (int i = 0; i < 8; ++i) {
        half8 hv = *(const half8*)(Srow + i * 128);   // fp16 scores
        half8 ev;
        floatx4 o0, o1;
        #pragma unroll
        for (int e = 0; e < 8; ++e) {
            float ex = __expf((float)hv[e] - mx);
            ev[e] = __builtin_bit_cast(_Float16, f2bf_u(ex));  // bf16 bits for PV
            float a = ex * iv;                                  // full-precision att
            if (e < 4) o0[e] = a; else o1[e - 4] = a;
        }
        *(half8*)(Srow + i * 128) = ev;
        *(floatx4*)(arow + i * 128)     = o0;
        *(floatx4*)(arow + i * 128 + 4) = o1;
    }
    __syncthreads();   // e-bits + rowinv visible to all before PV

    // ---- Phase 3: out = (e @ V) * inv_l. Each wave owns 32 of 128 d-cols ----
    // Fragment mappings verified R1/R2 — rt dimension removed only.
    int c0p = wid * 32;
    floatx4 o00 = {0.f,0.f,0.f,0.f}, o01 = o00;
    #pragma unroll 2
    for (int ks = 0; ks < 32; ++ks) {
        short8 a0 = __builtin_bit_cast(short8,
            *(const half8*)(S + (size_t)l15 * SSTRIDE + ks * 32 + quad * 8));
        short8 b0 = *(const short8*)(vp + (size_t)(c0p + l15) * TT + ks * 32 + quad * 8);
        short8 b1 = *(const short8*)(vp + (size_t)(c0p + 16 + l15) * TT + ks * 32 + quad * 8);
        o00 = __builtin_amdgcn_mfma_f32_16x16x32_bf16(a0, b0, o00, 0, 0, 0);
        o01 = __builtin_amdgcn_mfma_f32_16x16x32_bf16(a0, b1, o01, 0, 0, 0);
    }

    #pragma unroll
    for (int ct = 0; ct < 2; ++ct) {
        int col = c0p + ct * 16 + l15;     // d index 0..127
        floatx4 oo = ct ? o01 : o00;
        float agg = 0.f;
        #pragma unroll
        for (int r = 0; r < 4; ++r) {
            int rw = quad * 4 + r;
            float val = oo[r] * rowinv[rw];
            out[((size_t)(n * TT + t0 + rw)) * (HH * DD) + h * DD + col] = val;
            agg += val;
        }
        atomicAdd(outagg + n * (HH * DD) + h * DD + col, agg * (1.f / (float)TT));
    }
}

extern "C" void kernel_launch(void* const* d_in, const int* in_sizes, int n_in,
                              void* d_out, int out_size, void* d_ws, size_t ws_size,
                              hipStream_t stream) {
    const float* x    = (const float*)d_in[0];
    const int*   mask = (const int*)d_in[1];      // bool -> int32 (verified R1)
    const float* wts  = (const float*)d_in[2];
    const float* Wq = (const float*)d_in[3];
    const float* bq = (const float*)d_in[4];
    const float* Wk = (const float*)d_in[5];
    const float* bk = (const float*)d_in[6];
    const float* Wv = (const float*)d_in[7];
    const float* bv = (const float*)d_in[8];

    float* out    = (float*)d_out;                                  // [8,1024,1024]
    float* outagg = out + (size_t)NB * TT * HH * DD;                // [8,1024]
    float* att    = outagg + NB * HH * DD;                          // [8,8,1024,1024]

    unsigned short* qb = (unsigned short*)d_ws;                     // 16.78 MB each
    unsigned short* kb = qb + (size_t)NB * HH * TT * DD;
    unsigned short* vt = kb + (size_t)NB * HH * TT * DD;
    unsigned short* Wb = vt + (size_t)NB * HH * TT * DD;            // +0.75 MB

    hipMemsetAsync(outagg, 0, (size_t)NB * HH * DD * sizeof(float), stream);
    convw_kernel<<<384, 256, 0, stream>>>(Wq, Wk, Wv, Wb);
    proj_kernel<<<3072, 256, 0, stream>>>(x, Wb, bq, bk, bv, qb, kb, vt);
    attn_kernel<<<4096, 256, 16 * SSTRIDE * 2 + 64, stream>>>(
        qb, kb, vt, wts, mask, out, outagg, att);
}